// Round 11
// baseline (139.830 us; speedup 1.0000x reference)
//
#include <hip/hip_runtime.h>
#include <hip/hip_bf16.h>
#include <stdint.h>

// Fused attention block: S=2048, B=2, D=1024, H=16, HD=64.
// Round 11: flash = R10 body with in-block KV-split x2 (8 waves: group 0 does
// tiles 0-15, group 1 does 16-31, LDS combine; no global partials). XCD-aware
// bijective block swizzles on flash and both GEMMs.

typedef __bf16 bf16_t;
typedef __bf16 bf16x8 __attribute__((ext_vector_type(8)));
typedef __bf16 bf16x4 __attribute__((ext_vector_type(4)));
typedef __bf16 bf16x2 __attribute__((ext_vector_type(2)));
typedef float f32x4 __attribute__((ext_vector_type(4)));
typedef float f32x16 __attribute__((ext_vector_type(16)));
typedef uint32_t u32;

#define S_LEN 2048
#define BATCH 2
#define DMODEL 1024
#define NHEAD 16
#define HDIM 64
#define KVB 64
#define HITER 16               // KV tiles per wave-group (split x2)
// 0.125 (1/sqrt(64)) * log2(e), folded into Q so softmax uses exp2
#define Q_SCALE 0.1803368801111204f

__device__ inline void gld16(const void* g, void* l)
{
    __builtin_amdgcn_global_load_lds(
        (const __attribute__((address_space(1))) void*)g,
        (__attribute__((address_space(3))) void*)l, 16, 0, 0);
}

__device__ inline u32 pack2(float a, float b)
{
    union { bf16x2 h; u32 u; } c;
    c.h[0] = (bf16_t)a; c.h[1] = (bf16_t)b;
    return c.u;
}

// ---------------------------------------------------------------------------
__global__ __launch_bounds__(256) void xcvt_kernel(
    const float* __restrict__ in, bf16_t* __restrict__ out)
{
    size_t i = ((size_t)blockIdx.x * 256 + threadIdx.x) * 8;
    float4 f0 = *(const float4*)(in + i);
    float4 f1 = *(const float4*)(in + i + 4);
    bf16x8 o;
    o[0] = (bf16_t)f0.x; o[1] = (bf16_t)f0.y; o[2] = (bf16_t)f0.z; o[3] = (bf16_t)f0.w;
    o[4] = (bf16_t)f1.x; o[5] = (bf16_t)f1.y; o[6] = (bf16_t)f1.z; o[7] = (bf16_t)f1.w;
    *(bf16x8*)(out + i) = o;
}

// ---------------------------------------------------------------------------
__global__ __launch_bounds__(256) void transpose_convert(
    const float* __restrict__ in, bf16_t* __restrict__ out, int K, int N)
{
    __shared__ float tile[64][65];
    int n0 = blockIdx.x * 64, k0 = blockIdx.y * 64;
    int r = threadIdx.x >> 2;
    int c = (threadIdx.x & 3) * 16;
    const float* src = in + (size_t)(k0 + r) * N + n0 + c;
#pragma unroll
    for (int j = 0; j < 16; j += 4) {
        float4 f = *(const float4*)(src + j);
        tile[r][c + j + 0] = f.x;
        tile[r][c + j + 1] = f.y;
        tile[r][c + j + 2] = f.z;
        tile[r][c + j + 3] = f.w;
    }
    __syncthreads();
    bf16x8 o0, o1;
#pragma unroll
    for (int j = 0; j < 8; ++j) o0[j] = (bf16_t)tile[c + j][r];
#pragma unroll
    for (int j = 0; j < 8; ++j) o1[j] = (bf16_t)tile[c + 8 + j][r];
    bf16_t* dst = out + (size_t)(n0 + r) * K + k0 + c;
    *(bf16x8*)dst = o0;
    *(bf16x8*)(dst + 8) = o1;
}

// ---------------------------------------------------------------------------
// Fused QKV GEMM (R5 body) + bijective XCD swizzle: 4 m-panels per XCD.
// ---------------------------------------------------------------------------
__global__ __launch_bounds__(256) void gemm_qkv(
    const bf16_t* __restrict__ A, const bf16_t* __restrict__ WT,
    const float* __restrict__ bkv, const float* __restrict__ bq,
    bf16_t* __restrict__ outK, bf16_t* __restrict__ outV,
    bf16_t* __restrict__ outQ)
{
    const int K = 1024;
    __shared__ bf16_t As[128 * 32];
    __shared__ bf16_t Bs[128 * 32];
    int tid = threadIdx.x;
    int wave = tid >> 6, lane = tid & 63;
    int l15 = lane & 15, l4 = lane >> 4;
    // XCD swizzle: grid 768 = 8 XCD x 96; XCD c -> m-tiles [4c,4c+4) x all n
    int bid = blockIdx.x;
    int id = (bid & 7) * 96 + (bid >> 3);
    int m0 = (id / 24) * 128, n0 = (id % 24) * 128;
    int wr = (wave >> 1) * 64, wc = (wave & 1) * 64;

    bf16_t* ldsT = (wave < 2) ? As : Bs;
    const bf16_t* gbase = (wave < 2) ? A : WT;
    int rbase = (wave & 1) * 64;
    int tile0 = (wave < 2) ? m0 : n0;
    int srow = lane >> 2;
    int scol = (lane & 3) * 8;

    f32x4 acc[4][4] = {};

    for (int k0 = 0; k0 < K; k0 += 32) {
#pragma unroll
        for (int j = 0; j < 4; ++j) {
            const bf16_t* g = gbase +
                (size_t)(tile0 + rbase + j * 16 + srow) * K + k0 + scol;
            gld16(g, ldsT + (rbase + j * 16) * 32);
        }
        __syncthreads();
        bf16x8 af[4], bfr[4];
#pragma unroll
        for (int i = 0; i < 4; ++i)
            af[i] = *(const bf16x8*)&As[(wr + i * 16 + l15) * 32 + l4 * 8];
#pragma unroll
        for (int i = 0; i < 4; ++i)
            bfr[i] = *(const bf16x8*)&Bs[(wc + i * 16 + l15) * 32 + l4 * 8];
#pragma unroll
        for (int mi = 0; mi < 4; ++mi)
#pragma unroll
            for (int ni = 0; ni < 4; ++ni)
                acc[mi][ni] = __builtin_amdgcn_mfma_f32_16x16x32_bf16(
                    af[mi], bfr[ni], acc[mi][ni], 0, 0, 0);
        __syncthreads();
    }

#pragma unroll
    for (int mi = 0; mi < 4; ++mi) {
#pragma unroll
        for (int ni = 0; ni < 4; ++ni) {
#pragma unroll
            for (int e = 0; e < 4; ++e) {
                int gm = m0 + wr + mi * 16 + l4 * 4 + e;
                int gn = n0 + wc + ni * 16 + l15;
                float bsel = (gn < 2048) ? bkv[gn] : bq[gn - 2048];
                float v = acc[mi][ni][e] + bsel;
                int s = gm >> 1, b = gm & 1;
                int nn = gn & 1023;
                int h = nn >> 6, d = nn & 63;
                size_t idx = ((size_t)((b << 4) + h) * S_LEN + s) * HDIM + d;
                if (gn < 1024)
                    outK[idx] = (bf16_t)v;
                else if (gn < 2048)
                    outV[idx] = (bf16_t)v;
                else
                    outQ[idx] = (bf16_t)(v * Q_SCALE);
            }
        }
    }
}

// ---------------------------------------------------------------------------
// Output projection GEMM (R5 body) + bijective XCD swizzle.
// ---------------------------------------------------------------------------
__global__ __launch_bounds__(256) void gemm_out_kernel(
    const bf16_t* __restrict__ A, const bf16_t* __restrict__ WT,
    const float* __restrict__ bias, float* __restrict__ outF)
{
    const int K = 1024, N = 1024;
    __shared__ bf16_t As[64 * 32];
    __shared__ bf16_t Bs[128 * 32];
    int tid = threadIdx.x, wave = tid >> 6, lane = tid & 63;
    int l15 = lane & 15, l4 = lane >> 4;
    // XCD swizzle: grid 512 = 8 XCD x 64; XCD c -> m-tiles [8c,8c+8) x all n
    int bid = blockIdx.x;
    int id = (bid & 7) * 64 + (bid >> 3);
    int m0 = (id >> 3) * 64, n0 = (id & 7) * 128;
    int wc = wave * 32;
    int srow = lane >> 2, scol = (lane & 3) * 8;

    f32x4 acc[4][2] = {};

    for (int k0 = 0; k0 < K; k0 += 32) {
#pragma unroll
        for (int j = 0; j < 3; ++j) {
            int slot = wave * 3 + j;
            const bf16_t* g;
            bf16_t* l;
            if (slot < 4) {
                g = A + (size_t)(m0 + slot * 16 + srow) * K + k0 + scol;
                l = As + slot * 512;
            } else {
                g = WT + (size_t)(n0 + (slot - 4) * 16 + srow) * K + k0 + scol;
                l = Bs + (slot - 4) * 512;
            }
            gld16(g, l);
        }
        __syncthreads();
        bf16x8 af[4], bfr[2];
#pragma unroll
        for (int i = 0; i < 4; ++i)
            af[i] = *(const bf16x8*)&As[(i * 16 + l15) * 32 + l4 * 8];
#pragma unroll
        for (int i = 0; i < 2; ++i)
            bfr[i] = *(const bf16x8*)&Bs[(wc + i * 16 + l15) * 32 + l4 * 8];
#pragma unroll
        for (int mi = 0; mi < 4; ++mi)
#pragma unroll
            for (int ni = 0; ni < 2; ++ni)
                acc[mi][ni] = __builtin_amdgcn_mfma_f32_16x16x32_bf16(
                    af[mi], bfr[ni], acc[mi][ni], 0, 0, 0);
        __syncthreads();
    }

#pragma unroll
    for (int mi = 0; mi < 4; ++mi)
#pragma unroll
        for (int ni = 0; ni < 2; ++ni)
#pragma unroll
            for (int e = 0; e < 4; ++e) {
                int gm = m0 + mi * 16 + l4 * 4 + e;
                int gn = n0 + wc + ni * 16 + l15;
                outF[(size_t)gm * N + gn] = acc[mi][ni][e] + bias[gn];
            }
}

// ---------------------------------------------------------------------------
// Flash attention: R10 body, 8 waves = 2 KV-groups x 4 waves.
// Group g (waves 4g..4g+3) owns KV tiles [g*16, g*16+16) in its own LDS half;
// both groups cover the same 128 q rows. After the loop, group 1 dumps
// acc + l to LDS; group 0 combines (sums are exact: max-free softmax),
// normalizes, transposes, writes. Grid 512, XCD-chunked (4 heads/XCD).
// ---------------------------------------------------------------------------
__global__ __launch_bounds__(512) void flash_kernel(
    const bf16_t* __restrict__ Qb, const bf16_t* __restrict__ Kb,
    const bf16_t* __restrict__ Vb, bf16_t* __restrict__ AVb)
{
    __shared__ __align__(16) char lds[69632];   // 2 groups x 34816

    int bid = blockIdx.x;
    int id = (bid & 7) * 64 + (bid >> 3);   // XCD-chunked: 4 heads per XCD
    int bh = id >> 4;           // 0..31
    int qx = id & 15;           // 0..15

    int tid = threadIdx.x, wave = tid >> 6, lane = tid & 63;
    int group = wave >> 2;      // KV half
    int wg = wave & 3;          // wave within group
    int tg = tid & 255;         // thread within group
    int l31 = lane & 31, hi = lane >> 5;

    char* KsB = lds + group * 34816;           // 2 x [64][64] bf16, swizzled
    bf16_t* VtB = (bf16_t*)(KsB + 16384);      // 2 x [64][72] bf16

    const bf16_t* Qp = Qb + (size_t)bh * S_LEN * HDIM;
    const bf16_t* Kp = Kb + (size_t)bh * S_LEN * HDIM
                          + (size_t)group * HITER * KVB * HDIM;
    const bf16_t* Vp = Vb + (size_t)bh * S_LEN * HDIM
                          + (size_t)group * HITER * KVB * HDIM;

    int q0 = qx * 128 + wg * 32;

    bf16x8 qf[4];
#pragma unroll
    for (int dc = 0; dc < 4; ++dc)
        qf[dc] = *(const bf16x8*)(Qp + (size_t)(q0 + l31) * HDIM + dc * 16 + hi * 8);

    f32x16 acc0 = {}, acc1 = {};
    float l_run = 0.f;

    int krow = lane >> 3;
    int kcb = ((lane & 7) << 4) ^ (krow << 4);
    int vd = (tg >> 4) * 4;
    int vt = (tg & 15) * 2;
    bf16x4 vreg[2][2];
    int swz = (l31 & 7) << 4;

#define STAGE_K(it, buf)                                                       \
    {                                                                          \
        _Pragma("unroll")                                                      \
        for (int j = 0; j < 2; ++j) {                                          \
            int t = wg * 16 + j * 8 + krow;                                    \
            const char* g = (const char*)Kp +                                  \
                ((size_t)((it) * KVB + t) * HDIM) * 2 + kcb;                   \
            gld16(g, KsB + (buf) * 8192 + (wg * 16 + j * 8) * 128);            \
        }                                                                      \
    }
#define LOAD_V(it)                                                             \
    {                                                                          \
        const bf16_t* vb = Vp + (size_t)((it) * KVB + vt) * HDIM + vd;         \
        vreg[0][0] = *(const bf16x4*)vb;                                       \
        vreg[0][1] = *(const bf16x4*)(vb + HDIM);                              \
        vreg[1][0] = *(const bf16x4*)(vb + 32 * HDIM);                         \
        vreg[1][1] = *(const bf16x4*)(vb + 33 * HDIM);                         \
    }
#define WRITE_V(buf)                                                           \
    {                                                                          \
        bf16_t* vtb = VtB + (buf) * 4608;                                      \
        _Pragma("unroll")                                                      \
        for (int p = 0; p < 2; ++p) {                                          \
            _Pragma("unroll")                                                  \
            for (int j = 0; j < 4; ++j) {                                      \
                bf16x2 w;                                                      \
                w[0] = vreg[p][0][j];                                          \
                w[1] = vreg[p][1][j];                                          \
                *(bf16x2*)&vtb[(vd + j) * 72 + vt + 32 * p] = w;               \
            }                                                                  \
        }                                                                      \
    }

    STAGE_K(0, 0);
    LOAD_V(0);
    WRITE_V(0);
    __syncthreads();

    for (int it = 0; it < HITER; ++it) {
        int cur = it & 1;
        if (it + 1 < HITER) {
            STAGE_K(it + 1, cur ^ 1);
            LOAD_V(it + 1);
        }

        // ---- QK^T (S^T)
        f32x16 s0 = {}, s1 = {};
        __builtin_amdgcn_s_setprio(1);
#pragma unroll
        for (int dc = 0; dc < 4; ++dc) {
            bf16x8 k0 = *(const bf16x8*)(KsB + cur * 8192 + l31 * 128 +
                                         ((dc * 32 + hi * 16) ^ swz));
            bf16x8 k1 = *(const bf16x8*)(KsB + cur * 8192 + (32 + l31) * 128 +
                                         ((dc * 32 + hi * 16) ^ swz));
            s0 = __builtin_amdgcn_mfma_f32_32x32x16_bf16(k0, qf[dc], s0, 0, 0, 0);
            s1 = __builtin_amdgcn_mfma_f32_32x32x16_bf16(k1, qf[dc], s1, 0, 0, 0);
        }
        __builtin_amdgcn_s_setprio(0);

        // ---- max-free softmax: p = exp2(s); l += sum(p)
#pragma unroll
        for (int r = 0; r < 16; ++r) s0[r] = __builtin_amdgcn_exp2f(s0[r]);
#pragma unroll
        for (int r = 0; r < 16; ++r) s1[r] = __builtin_amdgcn_exp2f(s1[r]);
        float a8[8];
#pragma unroll
        for (int r = 0; r < 8; ++r)
            a8[r] = (s0[r] + s0[r + 8]) + (s1[r] + s1[r + 8]);
        float rs = ((a8[0] + a8[1]) + (a8[2] + a8[3])) +
                   ((a8[4] + a8[5]) + (a8[6] + a8[7]));
        rs += __shfl_xor(rs, 32);             // cross-half combine
        l_run += rs;

        // ---- P exchange (permlane32_swap, distinct operands) + PV
        __builtin_amdgcn_s_setprio(1);
#pragma unroll
        for (int s = 0; s < 4; ++s) {
            const int base = 8 * (s & 1);
            f32x16& P = (s < 2) ? s0 : s1;
            u32 a0 = pack2(P[base + 0], P[base + 1]);
            u32 a1 = pack2(P[base + 2], P[base + 3]);
            u32 b0 = pack2(P[base + 4], P[base + 5]);
            u32 b1 = pack2(P[base + 6], P[base + 7]);
            asm("v_permlane32_swap_b32 %0, %1" : "+v"(a0), "+v"(b0));
            asm("v_permlane32_swap_b32 %0, %1" : "+v"(a1), "+v"(b1));
            union { u32 u[4]; bf16x8 v; } pa;
            pa.u[0] = a0; pa.u[1] = a1; pa.u[2] = b0; pa.u[3] = b1;
            const bf16_t* vtb = VtB + cur * 4608;
            bf16x8 va0 = *(const bf16x8*)&vtb[l31 * 72 + s * 16 + hi * 8];
            bf16x8 va1 = *(const bf16x8*)&vtb[(32 + l31) * 72 + s * 16 + hi * 8];
            acc0 = __builtin_amdgcn_mfma_f32_32x32x16_bf16(va0, pa.v, acc0, 0, 0, 0);
            acc1 = __builtin_amdgcn_mfma_f32_32x32x16_bf16(va1, pa.v, acc1, 0, 0, 0);
        }
        __builtin_amdgcn_s_setprio(0);

        if (it + 1 < HITER) WRITE_V(cur ^ 1);
        __syncthreads();
    }

    // ---- combine: group 1 dumps acc + l; group 0 adds (exact: plain sums)
    float* xch = (float*)lds;                    // 4 waves x 2048 f32 = 32 KB
    float* lxch = (float*)(lds + 32768);         // 256 f32
    if (group == 1) {
        float* base = xch + wg * 2048;
#pragma unroll
        for (int r = 0; r < 16; ++r) base[r * 64 + lane] = acc0[r];
#pragma unroll
        for (int r = 0; r < 16; ++r) base[(16 + r) * 64 + lane] = acc1[r];
        lxch[wg * 64 + lane] = l_run;
    }
    __syncthreads();
    if (group == 0) {
        float* base = xch + wg * 2048;
#pragma unroll
        for (int r = 0; r < 16; ++r) acc0[r] += base[r * 64 + lane];
#pragma unroll
        for (int r = 0; r < 16; ++r) acc1[r] += base[(16 + r) * 64 + lane];
        l_run += lxch[wg * 64 + lane];

        // normalize + pack into per-wave transpose scratch (disjoint region)
        bf16_t* sw = (bf16_t*)(lds + 34816) + wg * (32 * 72);
        float inv = 1.0f / l_run;
#pragma unroll
        for (int g = 0; g < 4; ++g) {
            bf16x4 w0, w1;
#pragma unroll
            for (int e = 0; e < 4; ++e) {
                w0[e] = (bf16_t)(acc0[4 * g + e] * inv);
                w1[e] = (bf16_t)(acc1[4 * g + e] * inv);
            }
            int d0 = 8 * g + 4 * hi;
            *(bf16x4*)&sw[l31 * 72 + d0] = w0;
            *(bf16x4*)&sw[l31 * 72 + 32 + d0] = w1;
        }
    }
    __syncthreads();
    if (group == 0) {
        bf16_t* sw = (bf16_t*)(lds + 34816) + wg * (32 * 72);
        int q = lane >> 1, half = lane & 1;
        const bf16_t* srow = sw + q * 72 + half * 32;
        int s = q0 + q;
        int b = bh >> 4, h = bh & 15;
        bf16_t* dst = AVb + ((size_t)s * BATCH + b) * DMODEL + h * HDIM + half * 32;
#pragma unroll
        for (int k = 0; k < 4; ++k)
            *(bf16x8*)(dst + k * 8) = *(const bf16x8*)(srow + k * 8);
    }
}

// ---------------------------------------------------------------------------
extern "C" void kernel_launch(void* const* d_in, const int* in_sizes, int n_in,
                              void* d_out, int out_size, void* d_ws, size_t ws_size,
                              hipStream_t stream)
{
    const float* X   = (const float*)d_in[0];
    const float* Wkv = (const float*)d_in[1];
    const float* bkv = (const float*)d_in[2];
    const float* Wq  = (const float*)d_in[3];
    const float* bq  = (const float*)d_in[4];
    const float* Wp  = (const float*)d_in[5];
    const float* bp  = (const float*)d_in[6];
    float* out = (float*)d_out;

    char* ws = (char*)d_ws;
    size_t off = 0;
    auto alloc = [&](size_t bytes) -> void* {
        void* p = ws + off;
        off += (bytes + 255) & ~(size_t)255;
        return p;
    };
    bf16_t* WqkvT = (bf16_t*)alloc((size_t)3072 * 1024 * 2);  // [Wkv^T ; Wq^T]
    bf16_t* WpT   = (bf16_t*)alloc((size_t)1024 * 1024 * 2);
    bf16_t* Qb    = (bf16_t*)alloc((size_t)32 * S_LEN * HDIM * 2);
    bf16_t* Kb    = (bf16_t*)alloc((size_t)32 * S_LEN * HDIM * 2);
    bf16_t* Vb    = (bf16_t*)alloc((size_t)32 * S_LEN * HDIM * 2);
    bf16_t* Xbf   = (bf16_t*)alloc((size_t)4096 * 1024 * 2);
    bf16_t* AVb   = (bf16_t*)alloc((size_t)4096 * 1024 * 2);

    xcvt_kernel<<<2048, 256, 0, stream>>>(X, Xbf);
    transpose_convert<<<dim3(32, 16), 256, 0, stream>>>(Wkv, WqkvT, 1024, 2048);
    transpose_convert<<<dim3(16, 16), 256, 0, stream>>>(
        Wq, WqkvT + (size_t)2048 * 1024, 1024, 1024);
    transpose_convert<<<dim3(16, 16), 256, 0, stream>>>(Wp, WpT, 1024, 1024);

    gemm_qkv<<<768, 256, 0, stream>>>(Xbf, WqkvT, bkv, bq, Kb, Vb, Qb);
    flash_kernel<<<512, 512, 0, stream>>>(Qb, Kb, Vb, AVb);
    gemm_out_kernel<<<512, 256, 0, stream>>>(AVb, WpT, bp, out);
}

// Round 12
// 128.874 us; speedup vs baseline: 1.0850x; 1.0850x over previous
//
#include <hip/hip_runtime.h>
#include <hip/hip_bf16.h>
#include <stdint.h>

// Fused attention block: S=2048, B=2, D=1024, H=16, HD=64.
// Round 12: R10 base (best: 134.2us; flash 60.2us untouched). GEMMs upgraded
// to BK=64 with XOR-swizzled gload_lds staging (flash STAGE_K pattern):
// half the barriers, 32 MFMA per barrier pair, conflict-free 128B-stride reads.

typedef __bf16 bf16_t;
typedef __bf16 bf16x8 __attribute__((ext_vector_type(8)));
typedef __bf16 bf16x4 __attribute__((ext_vector_type(4)));
typedef __bf16 bf16x2 __attribute__((ext_vector_type(2)));
typedef float f32x4 __attribute__((ext_vector_type(4)));
typedef float f32x16 __attribute__((ext_vector_type(16)));
typedef uint32_t u32;

#define S_LEN 2048
#define BATCH 2
#define DMODEL 1024
#define NHEAD 16
#define HDIM 64
#define KVB 64
#define FNT (S_LEN / KVB)
// 0.125 (1/sqrt(64)) * log2(e), folded into Q so softmax uses exp2
#define Q_SCALE 0.1803368801111204f

__device__ inline void gld16(const void* g, void* l)
{
    __builtin_amdgcn_global_load_lds(
        (const __attribute__((address_space(1))) void*)g,
        (__attribute__((address_space(3))) void*)l, 16, 0, 0);
}

__device__ inline u32 pack2(float a, float b)
{
    union { bf16x2 h; u32 u; } c;
    c.h[0] = (bf16_t)a; c.h[1] = (bf16_t)b;
    return c.u;
}

// ---------------------------------------------------------------------------
__global__ __launch_bounds__(256) void xcvt_kernel(
    const float* __restrict__ in, bf16_t* __restrict__ out)
{
    size_t i = ((size_t)blockIdx.x * 256 + threadIdx.x) * 8;
    float4 f0 = *(const float4*)(in + i);
    float4 f1 = *(const float4*)(in + i + 4);
    bf16x8 o;
    o[0] = (bf16_t)f0.x; o[1] = (bf16_t)f0.y; o[2] = (bf16_t)f0.z; o[3] = (bf16_t)f0.w;
    o[4] = (bf16_t)f1.x; o[5] = (bf16_t)f1.y; o[6] = (bf16_t)f1.z; o[7] = (bf16_t)f1.w;
    *(bf16x8*)(out + i) = o;
}

// ---------------------------------------------------------------------------
__global__ __launch_bounds__(256) void transpose_convert(
    const float* __restrict__ in, bf16_t* __restrict__ out, int K, int N)
{
    __shared__ float tile[64][65];
    int n0 = blockIdx.x * 64, k0 = blockIdx.y * 64;
    int r = threadIdx.x >> 2;
    int c = (threadIdx.x & 3) * 16;
    const float* src = in + (size_t)(k0 + r) * N + n0 + c;
#pragma unroll
    for (int j = 0; j < 16; j += 4) {
        float4 f = *(const float4*)(src + j);
        tile[r][c + j + 0] = f.x;
        tile[r][c + j + 1] = f.y;
        tile[r][c + j + 2] = f.z;
        tile[r][c + j + 3] = f.w;
    }
    __syncthreads();
    bf16x8 o0, o1;
#pragma unroll
    for (int j = 0; j < 8; ++j) o0[j] = (bf16_t)tile[c + j][r];
#pragma unroll
    for (int j = 0; j < 8; ++j) o1[j] = (bf16_t)tile[c + 8 + j][r];
    bf16_t* dst = out + (size_t)(n0 + r) * K + k0 + c;
    *(bf16x8*)dst = o0;
    *(bf16x8*)(dst + 8) = o1;
}

// ---------------------------------------------------------------------------
// Fused QKV GEMM, BK=64, XOR-swizzled gload_lds staging.
// As/Bs: [128 rows][128 B] per buffer; LDS[row][c] = G[row][c ^ ((row&7)<<4)].
// ---------------------------------------------------------------------------
__global__ __launch_bounds__(256) void gemm_qkv(
    const bf16_t* __restrict__ A, const bf16_t* __restrict__ WT,
    const float* __restrict__ bkv, const float* __restrict__ bq,
    bf16_t* __restrict__ outK, bf16_t* __restrict__ outV,
    bf16_t* __restrict__ outQ)
{
    const int K = 1024;
    __shared__ __align__(16) char AsB[128 * 128];
    __shared__ __align__(16) char BsB[128 * 128];
    int tid = threadIdx.x;
    int wave = tid >> 6, lane = tid & 63;
    int l15 = lane & 15, l4 = lane >> 4;
    int m0 = blockIdx.x * 128, n0 = blockIdx.y * 128;
    int wr = (wave >> 1) * 64, wc = (wave & 1) * 64;

    char* ldsT = (wave < 2) ? AsB : BsB;
    const bf16_t* gbase = (wave < 2) ? A : WT;
    int rbase = (wave & 1) * 64;
    int tile0 = (wave < 2) ? m0 : n0;
    int srow = lane >> 3;                          // 0..7 within 8-row chunk
    int kcb = ((lane & 7) << 4) ^ (srow << 4);     // pre-swizzled col byte
    int rx = (l15 & 7) << 4;                       // read-side XOR

    f32x4 acc[4][4] = {};

    for (int k0 = 0; k0 < K; k0 += 64) {
#pragma unroll
        for (int j = 0; j < 8; ++j) {
            const char* g = (const char*)(gbase +
                (size_t)(tile0 + rbase + j * 8 + srow) * K + k0) + kcb;
            gld16(g, ldsT + (rbase + j * 8) * 128);
        }
        __syncthreads();
#pragma unroll
        for (int kk = 0; kk < 2; ++kk) {
            int cb = (kk * 64 + l4 * 16) ^ rx;
            bf16x8 af[4], bfr[4];
#pragma unroll
            for (int i = 0; i < 4; ++i)
                af[i] = *(const bf16x8*)(AsB + (wr + i * 16 + l15) * 128 + cb);
#pragma unroll
            for (int i = 0; i < 4; ++i)
                bfr[i] = *(const bf16x8*)(BsB + (wc + i * 16 + l15) * 128 + cb);
#pragma unroll
            for (int mi = 0; mi < 4; ++mi)
#pragma unroll
                for (int ni = 0; ni < 4; ++ni)
                    acc[mi][ni] = __builtin_amdgcn_mfma_f32_16x16x32_bf16(
                        af[mi], bfr[ni], acc[mi][ni], 0, 0, 0);
        }
        __syncthreads();
    }

#pragma unroll
    for (int mi = 0; mi < 4; ++mi) {
#pragma unroll
        for (int ni = 0; ni < 4; ++ni) {
#pragma unroll
            for (int e = 0; e < 4; ++e) {
                int gm = m0 + wr + mi * 16 + l4 * 4 + e;
                int gn = n0 + wc + ni * 16 + l15;
                float bsel = (gn < 2048) ? bkv[gn] : bq[gn - 2048];
                float v = acc[mi][ni][e] + bsel;
                int s = gm >> 1, b = gm & 1;
                int nn = gn & 1023;
                int h = nn >> 6, d = nn & 63;
                size_t idx = ((size_t)((b << 4) + h) * S_LEN + s) * HDIM + d;
                if (gn < 1024)
                    outK[idx] = (bf16_t)v;
                else if (gn < 2048)
                    outV[idx] = (bf16_t)v;
                else
                    outQ[idx] = (bf16_t)(v * Q_SCALE);
            }
        }
    }
}

// ---------------------------------------------------------------------------
// Output projection GEMM, 64x128 tile, BK=64, XOR-swizzled staging.
// ---------------------------------------------------------------------------
__global__ __launch_bounds__(256) void gemm_out_kernel(
    const bf16_t* __restrict__ A, const bf16_t* __restrict__ WT,
    const float* __restrict__ bias, float* __restrict__ outF)
{
    const int K = 1024, N = 1024;
    __shared__ __align__(16) char AsB[64 * 128];
    __shared__ __align__(16) char BsB[128 * 128];
    int tid = threadIdx.x, wave = tid >> 6, lane = tid & 63;
    int l15 = lane & 15, l4 = lane >> 4;
    int m0 = blockIdx.x * 64, n0 = blockIdx.y * 128;
    int wc = wave * 32;
    int srow = lane >> 3;
    int kcb = ((lane & 7) << 4) ^ (srow << 4);
    int rx = (l15 & 7) << 4;

    f32x4 acc[4][2] = {};

    for (int k0 = 0; k0 < K; k0 += 64) {
#pragma unroll
        for (int j = 0; j < 6; ++j) {
            int slot = wave * 6 + j;      // 0..23: 0-7 -> As, 8-23 -> Bs
            const bf16_t* g;
            char* l;
            if (slot < 8) {
                g = A + (size_t)(m0 + slot * 8 + srow) * K + k0;
                l = AsB + slot * 1024;
            } else {
                g = WT + (size_t)(n0 + (slot - 8) * 8 + srow) * K + k0;
                l = BsB + (slot - 8) * 1024;
            }
            gld16((const char*)g + kcb, l);
        }
        __syncthreads();
#pragma unroll
        for (int kk = 0; kk < 2; ++kk) {
            int cb = (kk * 64 + l4 * 16) ^ rx;
            bf16x8 af[4], bfr[2];
#pragma unroll
            for (int i = 0; i < 4; ++i)
                af[i] = *(const bf16x8*)(AsB + (i * 16 + l15) * 128 + cb);
#pragma unroll
            for (int i = 0; i < 2; ++i)
                bfr[i] = *(const bf16x8*)(BsB + (wc + i * 16 + l15) * 128 + cb);
#pragma unroll
            for (int mi = 0; mi < 4; ++mi)
#pragma unroll
                for (int ni = 0; ni < 2; ++ni)
                    acc[mi][ni] = __builtin_amdgcn_mfma_f32_16x16x32_bf16(
                        af[mi], bfr[ni], acc[mi][ni], 0, 0, 0);
        }
        __syncthreads();
    }

#pragma unroll
    for (int mi = 0; mi < 4; ++mi)
#pragma unroll
        for (int ni = 0; ni < 2; ++ni)
#pragma unroll
            for (int e = 0; e < 4; ++e) {
                int gm = m0 + mi * 16 + l4 * 4 + e;
                int gn = n0 + wc + ni * 16 + l15;
                outF[(size_t)gm * N + gn] = acc[mi][ni][e] + bias[gn];
            }
}

// ---------------------------------------------------------------------------
// Flash attention (R10 verbatim): swapped-QK^T 32x32, gload_lds K + XOR
// swizzle, reg-staged V, max-free softmax, permlane32_swap P-exchange.
// ---------------------------------------------------------------------------
__global__ __launch_bounds__(256) void flash_kernel(
    const bf16_t* __restrict__ Qb, const bf16_t* __restrict__ Kb,
    const bf16_t* __restrict__ Vb, bf16_t* __restrict__ AVb)
{
    __shared__ __align__(16) char lds[34816];
    char* KsB = lds;                         // 2 x [64][64] bf16, swizzled
    bf16_t* VtB = (bf16_t*)(lds + 16384);    // 2 x [64][72] bf16

    int bh = blockIdx.y;
    int tid = threadIdx.x, wave = tid >> 6, lane = tid & 63;
    int l31 = lane & 31, hi = lane >> 5;

    const bf16_t* Qp = Qb + (size_t)bh * S_LEN * HDIM;
    const bf16_t* Kp = Kb + (size_t)bh * S_LEN * HDIM;
    const bf16_t* Vp = Vb + (size_t)bh * S_LEN * HDIM;

    int q0 = blockIdx.x * 128 + wave * 32;

    bf16x8 qf[4];
#pragma unroll
    for (int dc = 0; dc < 4; ++dc)
        qf[dc] = *(const bf16x8*)(Qp + (size_t)(q0 + l31) * HDIM + dc * 16 + hi * 8);

    f32x16 acc0 = {}, acc1 = {};
    float l_run = 0.f;

    int krow = lane >> 3;
    int kcb = ((lane & 7) << 4) ^ (krow << 4);
    int vd = (tid >> 4) * 4;
    int vt = (tid & 15) * 2;
    bf16x4 vreg[2][2];
    int swz = (l31 & 7) << 4;

#define STAGE_K(it, buf)                                                       \
    {                                                                          \
        _Pragma("unroll")                                                      \
        for (int j = 0; j < 2; ++j) {                                          \
            int t = wave * 16 + j * 8 + krow;                                  \
            const char* g = (const char*)Kp +                                  \
                ((size_t)((it) * KVB + t) * HDIM) * 2 + kcb;                   \
            gld16(g, KsB + (buf) * 8192 + (wave * 16 + j * 8) * 128);          \
        }                                                                      \
    }
#define LOAD_V(it)                                                             \
    {                                                                          \
        const bf16_t* vb = Vp + (size_t)((it) * KVB + vt) * HDIM + vd;         \
        vreg[0][0] = *(const bf16x4*)vb;                                       \
        vreg[0][1] = *(const bf16x4*)(vb + HDIM);                              \
        vreg[1][0] = *(const bf16x4*)(vb + 32 * HDIM);                         \
        vreg[1][1] = *(const bf16x4*)(vb + 33 * HDIM);                         \
    }
#define WRITE_V(buf)                                                           \
    {                                                                          \
        bf16_t* vtb = VtB + (buf) * 4608;                                      \
        _Pragma("unroll")                                                      \
        for (int p = 0; p < 2; ++p) {                                          \
            _Pragma("unroll")                                                  \
            for (int j = 0; j < 4; ++j) {                                      \
                bf16x2 w;                                                      \
                w[0] = vreg[p][0][j];                                          \
                w[1] = vreg[p][1][j];                                          \
                *(bf16x2*)&vtb[(vd + j) * 72 + vt + 32 * p] = w;               \
            }                                                                  \
        }                                                                      \
    }

    STAGE_K(0, 0);
    LOAD_V(0);
    WRITE_V(0);
    __syncthreads();

    for (int it = 0; it < FNT; ++it) {
        int cur = it & 1;
        if (it + 1 < FNT) {
            STAGE_K(it + 1, cur ^ 1);
            LOAD_V(it + 1);
        }

        // ---- QK^T (S^T)
        f32x16 s0 = {}, s1 = {};
        __builtin_amdgcn_s_setprio(1);
#pragma unroll
        for (int dc = 0; dc < 4; ++dc) {
            bf16x8 k0 = *(const bf16x8*)(KsB + cur * 8192 + l31 * 128 +
                                         ((dc * 32 + hi * 16) ^ swz));
            bf16x8 k1 = *(const bf16x8*)(KsB + cur * 8192 + (32 + l31) * 128 +
                                         ((dc * 32 + hi * 16) ^ swz));
            s0 = __builtin_amdgcn_mfma_f32_32x32x16_bf16(k0, qf[dc], s0, 0, 0, 0);
            s1 = __builtin_amdgcn_mfma_f32_32x32x16_bf16(k1, qf[dc], s1, 0, 0, 0);
        }
        __builtin_amdgcn_s_setprio(0);

        // ---- max-free softmax: p = exp2(s); l += sum(p)
#pragma unroll
        for (int r = 0; r < 16; ++r) s0[r] = __builtin_amdgcn_exp2f(s0[r]);
#pragma unroll
        for (int r = 0; r < 16; ++r) s1[r] = __builtin_amdgcn_exp2f(s1[r]);
        float a8[8];
#pragma unroll
        for (int r = 0; r < 8; ++r)
            a8[r] = (s0[r] + s0[r + 8]) + (s1[r] + s1[r + 8]);
        float rs = ((a8[0] + a8[1]) + (a8[2] + a8[3])) +
                   ((a8[4] + a8[5]) + (a8[6] + a8[7]));
        rs += __shfl_xor(rs, 32);             // cross-half combine
        l_run += rs;

        // ---- P exchange (permlane32_swap, distinct operands) + PV
        __builtin_amdgcn_s_setprio(1);
#pragma unroll
        for (int s = 0; s < 4; ++s) {
            const int base = 8 * (s & 1);
            f32x16& P = (s < 2) ? s0 : s1;
            u32 a0 = pack2(P[base + 0], P[base + 1]);
            u32 a1 = pack2(P[base + 2], P[base + 3]);
            u32 b0 = pack2(P[base + 4], P[base + 5]);
            u32 b1 = pack2(P[base + 6], P[base + 7]);
            asm("v_permlane32_swap_b32 %0, %1" : "+v"(a0), "+v"(b0));
            asm("v_permlane32_swap_b32 %0, %1" : "+v"(a1), "+v"(b1));
            union { u32 u[4]; bf16x8 v; } pa;
            pa.u[0] = a0; pa.u[1] = a1; pa.u[2] = b0; pa.u[3] = b1;
            const bf16_t* vtb = VtB + cur * 4608;
            bf16x8 va0 = *(const bf16x8*)&vtb[l31 * 72 + s * 16 + hi * 8];
            bf16x8 va1 = *(const bf16x8*)&vtb[(32 + l31) * 72 + s * 16 + hi * 8];
            acc0 = __builtin_amdgcn_mfma_f32_32x32x16_bf16(va0, pa.v, acc0, 0, 0, 0);
            acc1 = __builtin_amdgcn_mfma_f32_32x32x16_bf16(va1, pa.v, acc1, 0, 0, 0);
        }
        __builtin_amdgcn_s_setprio(0);

        if (it + 1 < FNT) WRITE_V(cur ^ 1);
        __syncthreads();
    }

    // ---- epilogue
    bf16_t* sw = (bf16_t*)lds + wave * (32 * 72);
    float inv = 1.0f / l_run;
#pragma unroll
    for (int g = 0; g < 4; ++g) {
        bf16x4 w0, w1;
#pragma unroll
        for (int e = 0; e < 4; ++e) {
            w0[e] = (bf16_t)(acc0[4 * g + e] * inv);
            w1[e] = (bf16_t)(acc1[4 * g + e] * inv);
        }
        int d0 = 8 * g + 4 * hi;
        *(bf16x4*)&sw[l31 * 72 + d0] = w0;
        *(bf16x4*)&sw[l31 * 72 + 32 + d0] = w1;
    }
    __syncthreads();
    {
        int q = lane >> 1, half = lane & 1;
        const bf16_t* srow = sw + q * 72 + half * 32;
        int s = q0 + q;
        int b = bh >> 4, h = bh & 15;
        bf16_t* dst = AVb + ((size_t)s * BATCH + b) * DMODEL + h * HDIM + half * 32;
#pragma unroll
        for (int k = 0; k < 4; ++k)
            *(bf16x8*)(dst + k * 8) = *(const bf16x8*)(srow + k * 8);
    }
}

// ---------------------------------------------------------------------------
extern "C" void kernel_launch(void* const* d_in, const int* in_sizes, int n_in,
                              void* d_out, int out_size, void* d_ws, size_t ws_size,
                              hipStream_t stream)
{
    const float* X   = (const float*)d_in[0];
    const float* Wkv = (const float*)d_in[1];
    const float* bkv = (const float*)d_in[2];
    const float* Wq  = (const float*)d_in[3];
    const float* bq  = (const float*)d_in[4];
    const float* Wp  = (const float*)d_in[5];
    const float* bp  = (const float*)d_in[6];
    float* out = (float*)d_out;

    char* ws = (char*)d_ws;
    size_t off = 0;
    auto alloc = [&](size_t bytes) -> void* {
        void* p = ws + off;
        off += (bytes + 255) & ~(size_t)255;
        return p;
    };
    bf16_t* WqkvT = (bf16_t*)alloc((size_t)3072 * 1024 * 2);  // [Wkv^T ; Wq^T]
    bf16_t* WpT   = (bf16_t*)alloc((size_t)1024 * 1024 * 2);
    bf16_t* Qb    = (bf16_t*)alloc((size_t)32 * S_LEN * HDIM * 2);
    bf16_t* Kb    = (bf16_t*)alloc((size_t)32 * S_LEN * HDIM * 2);
    bf16_t* Vb    = (bf16_t*)alloc((size_t)32 * S_LEN * HDIM * 2);
    bf16_t* Xbf   = (bf16_t*)alloc((size_t)4096 * 1024 * 2);
    bf16_t* AVb   = (bf16_t*)alloc((size_t)4096 * 1024 * 2);

    xcvt_kernel<<<2048, 256, 0, stream>>>(X, Xbf);
    transpose_convert<<<dim3(32, 16), 256, 0, stream>>>(Wkv, WqkvT, 1024, 2048);
    transpose_convert<<<dim3(16, 16), 256, 0, stream>>>(
        Wq, WqkvT + (size_t)2048 * 1024, 1024, 1024);
    transpose_convert<<<dim3(16, 16), 256, 0, stream>>>(Wp, WpT, 1024, 1024);

    gemm_qkv<<<dim3(32, 24), 256, 0, stream>>>(Xbf, WqkvT, bkv, bq, Kb, Vb, Qb);
    flash_kernel<<<dim3(S_LEN / 128, 32), 256, 0, stream>>>(Qb, Kb, Vb, AVb);
    gemm_out_kernel<<<dim3(64, 8), 256, 0, stream>>>(AVb, WpT, bp, out);
}